// Round 9
// baseline (60.085 us; speedup 1.0000x reference)
//
#include <hip/hip_runtime.h>

// SpatioTemporalGAT  (N=4096, F=64, H=64, K=2 heads, O=32; temporal input unused)
//
// R8 lesson (decisive counters at last): fused adj stream = 43.4us @ 900GB/s,
// VALU 22%, MFMA 3.5% -- nothing saturated. The adj load instruction spanned
// 4KB at lane-stride 64B (64 lines/instr, 16B used per line): low per-instr
// density. Every slow adj variant shared this trait; the 6.8TB/s fill and
// 6.3TB/s copy ubench are lane-contiguous. Theory: VMEM sustains ~N instrs in
// flight per CU; BW ~ N * useful-bytes-per-instr / latency.
// Fix: (1) fully-coalesced adj instrs (lane i <-> contiguous 16B, 1KB/instr);
// (2) nibble repack via LDS (lane packs 4 nibbles -> u16; consumer extracts
// its 8 q-bits from one u32 read); (3) depth-2 chunk prefetch (loads for c+2
// issue before compute of c; pack of c+1 waits after compute).
//
// prep_small — [0,64): Wh GEMM + e1/e2 node factors + whB B-frag store;
//              [64,169): LSTM/fc weight packing (B-frag layout).
// gat_attn   — chunk-pipelined {coalesced adj load || masked-softmax+PV mfma};
//              exp-free hot loop (w = pp>1 ? e1p*e1q : e2p*e2q); combine 16
//              wave partials; fused LSTM gates GEMM + nonlinearity + fc GEMM.

#define NN 4096

typedef __attribute__((ext_vector_type(8))) short bf16x8;
typedef __attribute__((ext_vector_type(4))) float f32x4;

__device__ inline unsigned short bf_rne(float f) {
    unsigned u = __float_as_uint(f);
    u += 0x7fffu + ((u >> 16) & 1u);
    return (unsigned short)(u >> 16);
}

__device__ inline unsigned cvt_pk_bf16(float lo, float hi) {
    unsigned r;
    asm("v_cvt_pk_bf16_f32 %0, %1, %2" : "=v"(r) : "v"(lo), "v"(hi));
    return r;
}

__device__ inline float sigf(float x) { return 1.f / (1.f + __expf(-x)); }

__device__ inline unsigned nib4(const int4 a) {
    unsigned m = 0;
    m |= (a.x > 0) ? 1u : 0u;
    m |= (a.y > 0) ? 2u : 0u;
    m |= (a.z > 0) ? 4u : 0u;
    m |= (a.w > 0) ? 8u : 0u;
    return m;
}

__global__ __launch_bounds__(256) void prep_small(
    const float* __restrict__ X, const float* __restrict__ Wg,
    const float* __restrict__ a_src, const float* __restrict__ a_dst,
    const float* __restrict__ W_ih, const float* __restrict__ b_ih,
    const float* __restrict__ b_hh, const float* __restrict__ fc_W,
    unsigned short* __restrict__ whB, float* __restrict__ e1s,
    float* __restrict__ e2s, float* __restrict__ e1d, float* __restrict__ e2d,
    unsigned short* __restrict__ Wpk, unsigned short* __restrict__ fcb,
    float* __restrict__ biasg)
{
    __shared__ float X_lds[64][64];
    __shared__ float Wh_lds[64][65];
    __shared__ float spart[64][4][2];
    const int t = threadIdx.x;
    const int bid = blockIdx.x;

    if (bid >= 64) {
        // ---- weight packing ----
        const int idx = (bid - 64) * 256 + t;
        if (idx < 24576) {
            const int j = idx & 7, lane = (idx >> 3) & 63;
            const int k0 = (idx >> 9) & 3, tt = idx >> 11;
            const int jj = tt * 16 + (lane & 15);
            const int m = k0 * 32 + (lane >> 4) * 8 + j;
            const int sr = (jj < 64) ? jj : 64 + jj;        // skip dead f rows
            Wpk[idx] = bf_rne(W_ih[sr * 128 + m]);
        } else if (idx < 26624) {
            const int o = idx - 24576;                      // fc frag: 2 tiles
            const int j = o & 7, lane = (o >> 3) & 63;
            const int k0 = (o >> 9) & 1, tt = o >> 10;
            const int row = tt * 16 + (lane & 15);
            const int m = k0 * 32 + (lane >> 4) * 8 + j;
            fcb[o] = bf_rne(fc_W[row * 64 + m]);
        } else if (idx < 26816) {
            const int j = idx - 26624;
            const int sr = (j < 64) ? j : 64 + j;
            biasg[j] = b_ih[sr] + b_hh[sr];
        }
        return;
    }

    // ---- Wh GEMM + e-factors + whB B-frag store ----
    const int n0 = bid * 64;
#pragma unroll
    for (int i = 0; i < 16; ++i) {
        int idx = t + i * 256;
        X_lds[idx >> 6][idx & 63] = X[n0 * 64 + idx];
    }
    __syncthreads();
    const int h = t & 63, rg = t >> 6;
    for (int k = 0; k < 2; ++k) {
        float acc[16];
#pragma unroll
        for (int r = 0; r < 16; ++r) acc[r] = 0.f;
        for (int f0 = 0; f0 < 64; f0 += 4) {
            const float4 w4 = *(const float4*)&Wg[(k * 64 + h) * 64 + f0];
#pragma unroll
            for (int r = 0; r < 16; ++r) {
                const float4 x4 = *(const float4*)&X_lds[rg * 16 + r][f0];
                acc[r] += w4.x * x4.x + w4.y * x4.y + w4.z * x4.z + w4.w * x4.w;
            }
        }
        if (k) __syncthreads();
#pragma unroll
        for (int r = 0; r < 16; ++r) Wh_lds[rg * 16 + r][h] = acc[r];
        __syncthreads();
        {   // per-node logit terms (partial over 16 h each)
            const int r = t & 63, qa = t >> 6;
            float ps = 0.f, pd = 0.f;
#pragma unroll
            for (int i = 0; i < 16; ++i) {
                const int hh = qa * 16 + i;
                const float v = Wh_lds[r][hh];
                ps += v * a_src[k * 64 + hh];
                pd += v * a_dst[k * 64 + hh];
            }
            spart[r][qa][0] = ps;
            spart[r][qa][1] = pd;
        }
        {   // bf16 store in MFMA B-frag order:
            // flat = ((k*4+f)*128+qb)*512 + (qg*16+n)*8 + j
#pragma unroll
            for (int pid = t; pid < 512; pid += 256) {
                const int n = pid & 15, qg = (pid >> 4) & 3;
                const int qb_loc = (pid >> 6) & 1, f = pid >> 7;
                const int qb = (n0 >> 5) + qb_loc;
                unsigned pk[4];
#pragma unroll
                for (int i = 0; i < 4; ++i) {
                    const int r = qb_loc * 32 + qg * 8 + 2 * i;
                    unsigned lo = bf_rne(Wh_lds[r][f * 16 + n]);
                    unsigned hi = bf_rne(Wh_lds[r + 1][f * 16 + n]);
                    pk[i] = lo | (hi << 16);
                }
                uint4* dst = (uint4*)&whB[(((k * 4 + f) * 128 + qb) * 512) + (qg * 16 + n) * 8];
                *dst = make_uint4(pk[0], pk[1], pk[2], pk[3]);
            }
        }
        __syncthreads();
        if (t < 64) {
            float s0 = spart[t][0][0] + spart[t][1][0] + spart[t][2][0] + spart[t][3][0];
            float s1 = spart[t][0][1] + spart[t][1][1] + spart[t][2][1] + spart[t][3][1];
            e1s[k * NN + n0 + t] = __expf(s0);
            e2s[k * NN + n0 + t] = __expf(0.2f * s0);
            e1d[k * NN + n0 + t] = __expf(s1);
            e2d[k * NN + n0 + t] = __expf(0.2f * s1);
        }
    }
}

__global__ __launch_bounds__(1024) void gat_attn(
    const int* __restrict__ adj,
    const unsigned short* __restrict__ whB,
    const float* __restrict__ e1s, const float* __restrict__ e2s,
    const float* __restrict__ e1d, const float* __restrict__ e2d,
    const unsigned short* __restrict__ Wpk, const unsigned short* __restrict__ fcb,
    const float* __restrict__ biasg, const float* __restrict__ fc_b,
    float* __restrict__ out)
{
    __shared__ float S_all[16][2][16][64];              // 128 KB wave partials
    __shared__ float z_all[16][2][16];                  // 2 KB
    __shared__ unsigned msk32[2][16][37];               // 4.7 KB dbuf mask tiles
    // (u16 view: lane l of wave w writes word [w][l]; stride 37 dwords ->
    //  consumer reads msk32[rloc][col]: banks (5*rloc+col)%32, rloc 0..15
    //  distinct, residual aliasing <=2-way = free)
    // post-combine aliases into dead S_all space:
    unsigned short* h_lds = (unsigned short*)&S_all[0][0][0][0];      // [16][136] bf16
    float* gate_lds = (float*)((char*)&S_all[0][0][0][0] + 4608);     // [3][16][68] f32

    const int tid = threadIdx.x;
    const int wave = tid >> 6, lane = tid & 63;
    const int rloc = lane & 15, qg = lane >> 4;
    const int p0 = blockIdx.x * 16;
    const int p = p0 + rloc;

    // wave w streams adj row p0+w, fully coalesced: instr o of chunk c ->
    // lane i reads int4 (c*256 + o*64 + i), i.e. contiguous 1KB per instr.
    const int4* __restrict__ arow4 = (const int4*)(adj + (long)(p0 + wave) * NN);

    // per-lane row factors
    const float e1p0 = e1d[p], e2p0 = e2d[p];
    const float e1p1 = e1d[NN + p], e2p1 = e2d[NN + p];
    const unsigned short* __restrict__ whB_l = whB + lane * 8;

    f32x4 acc[2][4];
#pragma unroll
    for (int k = 0; k < 2; ++k)
#pragma unroll
        for (int f = 0; f < 4; ++f)
            acc[k][f] = (f32x4){0.f, 0.f, 0.f, 0.f};
    float z0 = 0.f, z1 = 0.f;

    // ---- prologue: issue chunks 0 and 1; pack+stage chunk 0 ----
    int4 pre[2][4];
#pragma unroll
    for (int o = 0; o < 4; ++o) pre[0][o] = arow4[o * 64 + lane];
#pragma unroll
    for (int o = 0; o < 4; ++o) pre[1][o] = arow4[256 + o * 64 + lane];
    {
        const unsigned pk = nib4(pre[0][0]) | (nib4(pre[0][1]) << 4) |
                            (nib4(pre[0][2]) << 8) | (nib4(pre[0][3]) << 12);
        ((unsigned short*)&msk32[0][wave][0])[lane] = (unsigned short)pk;
    }
    __syncthreads();

#pragma unroll
    for (int c = 0; c < 4; ++c) {
        // issue chunk c+2's loads into the slot freed by chunk c's pack
        if (c + 2 < 4) {
#pragma unroll
            for (int o = 0; o < 4; ++o)
                pre[c & 1][o] = arow4[(c + 2) * 256 + o * 64 + lane];
        }
        // ---- compute chunk c: wave handles q in [c*1024 + wave*64, +64) ----
#pragma unroll
        for (int kk = 0; kk < 2; ++kk) {
            const int q0 = c * 1024 + wave * 64 + kk * 32 + qg * 8;
            const int qb = c * 32 + wave * 2 + kk;
            const unsigned W = msk32[c & 1][rloc][(wave & 3) * 8 + kk * 4 + qg];
            const unsigned osel = (wave >> 2) * 4;
            const unsigned byte8 = ((W >> osel) & 0xFu) |
                                   (((W >> (16 + osel)) & 0xFu) << 4);
            // q-side factors (L1/L2-hot broadcast arrays)
            const float4 qa0 = *(const float4*)(e1s + q0);
            const float4 qa1 = *(const float4*)(e1s + q0 + 4);
            const float4 qb0 = *(const float4*)(e2s + q0);
            const float4 qb1 = *(const float4*)(e2s + q0 + 4);
            const float4 qc0 = *(const float4*)(e1s + NN + q0);
            const float4 qc1 = *(const float4*)(e1s + NN + q0 + 4);
            const float4 qd0 = *(const float4*)(e2s + NN + q0);
            const float4 qd1 = *(const float4*)(e2s + NN + q0 + 4);
            const float q1v0[8] = {qa0.x, qa0.y, qa0.z, qa0.w, qa1.x, qa1.y, qa1.z, qa1.w};
            const float q2v0[8] = {qb0.x, qb0.y, qb0.z, qb0.w, qb1.x, qb1.y, qb1.z, qb1.w};
            const float q1v1[8] = {qc0.x, qc0.y, qc0.z, qc0.w, qc1.x, qc1.y, qc1.z, qc1.w};
            const float q2v1[8] = {qd0.x, qd0.y, qd0.z, qd0.w, qd1.x, qd1.y, qd1.z, qd1.w};
            float w0a[8], w1a[8];
#pragma unroll
            for (int j = 0; j < 8; ++j) {
                const bool on = (byte8 & (1u << j)) != 0u;
                // w = exp(lrelu(sd+ss)) ; pp=exp(sd+ss) ; pp>1 <=> sd+ss>0
                const float pp0 = e1p0 * q1v0[j];
                float w0 = pp0 > 1.f ? pp0 : e2p0 * q2v0[j];
                w0 = on ? w0 : 0.f;
                z0 += w0;
                w0a[j] = w0;
                const float pp1 = e1p1 * q1v1[j];
                float w1 = pp1 > 1.f ? pp1 : e2p1 * q2v1[j];
                w1 = on ? w1 : 0.f;
                z1 += w1;
                w1a[j] = w1;
            }
            union { bf16x8 v; unsigned w[4]; } fa0, fa1;
#pragma unroll
            for (int i = 0; i < 4; ++i) {
                fa0.w[i] = cvt_pk_bf16(w0a[2 * i], w0a[2 * i + 1]);
                fa1.w[i] = cvt_pk_bf16(w1a[2 * i], w1a[2 * i + 1]);
            }
#pragma unroll
            for (int f = 0; f < 4; ++f) {
                const bf16x8 b0 = *(const bf16x8*)(whB_l + ((f * 128 + qb) << 9));
                acc[0][f] = __builtin_amdgcn_mfma_f32_16x16x32_bf16(fa0.v, b0, acc[0][f], 0, 0, 0);
                const bf16x8 b1 = *(const bf16x8*)(whB_l + (((4 + f) * 128 + qb) << 9));
                acc[1][f] = __builtin_amdgcn_mfma_f32_16x16x32_bf16(fa1.v, b1, acc[1][f], 0, 0, 0);
            }
        }
        // pack chunk c+1 (vmcnt wait lands AFTER compute) into buf (c+1)&1;
        // that buffer's last readers (chunk c-1) passed the previous barrier.
        if (c < 3) {
            const unsigned pk = nib4(pre[(c + 1) & 1][0]) | (nib4(pre[(c + 1) & 1][1]) << 4) |
                                (nib4(pre[(c + 1) & 1][2]) << 8) | (nib4(pre[(c + 1) & 1][3]) << 12);
            ((unsigned short*)&msk32[(c + 1) & 1][wave][0])[lane] = (unsigned short)pk;
            __syncthreads();
        }
    }
    // z: sum the 4 q-groups (lanes l, l^16, l^32, l^48 share a row)
    z0 += __shfl_xor(z0, 16); z0 += __shfl_xor(z0, 32);
    z1 += __shfl_xor(z1, 16); z1 += __shfl_xor(z1, 32);
    if (lane < 16) { z_all[wave][0][lane] = z0; z_all[wave][1][lane] = z1; }
    // D-frag layout: row=(l>>4)*4+j, col=l&15
#pragma unroll
    for (int k = 0; k < 2; ++k)
#pragma unroll
        for (int f = 0; f < 4; ++f)
#pragma unroll
            for (int j = 0; j < 4; ++j)
                S_all[wave][k][qg * 4 + j][f * 16 + rloc] = acc[k][f][j];
    __syncthreads();
    // combine 16 wave-partials, normalize, elu -> registers
    float vreg[2]; int vk[2], vr[2], vh[2];
#pragma unroll
    for (int i = 0; i < 2; ++i) {
        const int idx = tid + i * 1024;
        const int k = idx >> 10, rr = (idx >> 6) & 15, hh = idx & 63;
        float s = 0.f, z = 0.f;
#pragma unroll
        for (int w = 0; w < 16; ++w) {
            s += S_all[w][k][rr][hh];
            z += z_all[w][k][rr];
        }
        float v = s / z;
        vreg[i] = v > 0.f ? v : expm1f(v);
        vk[i] = k; vr[i] = rr; vh[i] = hh;
    }
    __syncthreads();    // all S_all reads done; safe to reuse as h_lds/gate_lds
    // h tile bf16 [node][k*64+h], padded row 136 (272B, 16B-aligned rows)
#pragma unroll
    for (int i = 0; i < 2; ++i)
        h_lds[vr[i] * 136 + vk[i] * 64 + vh[i]] = bf_rne(vreg[i]);
    __syncthreads();

    // ---- fused LSTM gates GEMM: 12 waves, one 16-col gate tile each ----
    const int c2 = lane & 15, g4 = lane >> 4;
    if (wave < 12) {
        const int t = wave;
        f32x4 ga = (f32x4){0.f, 0.f, 0.f, 0.f};
#pragma unroll
        for (int k0 = 0; k0 < 4; ++k0) {
            const bf16x8 a = *(const bf16x8*)&h_lds[c2 * 136 + k0 * 32 + g4 * 8];
            const bf16x8 b = *(const bf16x8*)&Wpk[((t * 4 + k0) * 64 + lane) * 8];
            ga = __builtin_amdgcn_mfma_f32_16x16x32_bf16(a, b, ga, 0, 0, 0);
        }
        const float bb = biasg[t * 16 + c2];
#pragma unroll
        for (int j = 0; j < 4; ++j)
            gate_lds[(t >> 2) * 1088 + (g4 * 4 + j) * 68 + (t & 3) * 16 + c2] = ga[j] + bb;
    }
    __syncthreads();
    // ---- LSTM nonlinearity: ht = sig(o)*tanh(sig(i)*tanh(g)) ----
    {
        const int n = tid >> 6, hh = tid & 63;
        const float iv = gate_lds[n * 68 + hh];
        const float gv = gate_lds[1088 + n * 68 + hh];
        const float ov = gate_lds[2176 + n * 68 + hh];
        const float cv = sigf(iv) * tanhf(gv);
        const float htv = sigf(ov) * tanhf(cv);
        __syncthreads();
        h_lds[n * 136 + hh] = bf_rne(htv);   // reuse h_lds (gates consumed h)
    }
    __syncthreads();
    // ---- fc GEMM: waves 0,1 -> out[16 nodes][32] ----
    if (wave < 2) {
        const int t2 = wave;
        f32x4 fa = (f32x4){0.f, 0.f, 0.f, 0.f};
#pragma unroll
        for (int k0 = 0; k0 < 2; ++k0) {
            const bf16x8 a = *(const bf16x8*)&h_lds[c2 * 136 + k0 * 32 + g4 * 8];
            const bf16x8 b = *(const bf16x8*)&fcb[((t2 * 2 + k0) * 64 + lane) * 8];
            fa = __builtin_amdgcn_mfma_f32_16x16x32_bf16(a, b, fa, 0, 0, 0);
        }
        const float fb = fc_b[t2 * 16 + c2];
#pragma unroll
        for (int j = 0; j < 4; ++j)
            out[(p0 + g4 * 4 + j) * 32 + t2 * 16 + c2] = fa[j] + fb;
    }
}

extern "C" void kernel_launch(void* const* d_in, const int* in_sizes, int n_in,
                              void* d_out, int out_size, void* d_ws, size_t ws_size,
                              hipStream_t stream) {
    const float* X     = (const float*)d_in[0];
    const int*   adj   = (const int*)d_in[1];
    // d_in[2] temporal_features: unused by the reference
    const float* Wg    = (const float*)d_in[3];
    const float* a_src = (const float*)d_in[4];
    const float* a_dst = (const float*)d_in[5];
    const float* W_ih  = (const float*)d_in[6];
    // d_in[7] W_hh: unused (h0 == 0)
    const float* b_ih  = (const float*)d_in[8];
    const float* b_hh  = (const float*)d_in[9];
    const float* fc_W  = (const float*)d_in[10];
    const float* fc_b  = (const float*)d_in[11];
    float* out = (float*)d_out;

    char* ws = (char*)d_ws;
    unsigned short* whB = (unsigned short*)ws;                       // 1 MB
    float* e1s = (float*)(ws + (1 << 20));                           // 32 KB
    float* e2s = (float*)(ws + (1 << 20) + (32 << 10));              // 32 KB
    float* e1d = (float*)(ws + (1 << 20) + (64 << 10));              // 32 KB
    float* e2d = (float*)(ws + (1 << 20) + (96 << 10));              // 32 KB
    char* ws2 = ws + (1 << 20) + (128 << 10);
    unsigned short* Wpk = (unsigned short*)ws2;                      // 48 KB
    unsigned short* fcb = (unsigned short*)(ws2 + (48 << 10));       // 4 KB
    float* biasg = (float*)(ws2 + (52 << 10));                       // 768 B

    hipLaunchKernelGGL(prep_small, dim3(169), dim3(256), 0, stream,
                       X, Wg, a_src, a_dst, W_ih, b_ih, b_hh, fc_W,
                       whB, e1s, e2s, e1d, e2d, Wpk, fcb, biasg);
    hipLaunchKernelGGL(gat_attn, dim3(256), dim3(1024), 0, stream,
                       adj, whB, e1s, e2s, e1d, e2d, Wpk, fcb, biasg, fc_b, out);
}

// Round 11
// 56.557 us; speedup vs baseline: 1.0624x; 1.0624x over previous
//
#include <hip/hip_runtime.h>

// SpatioTemporalGAT  (N=4096, F=64, H=64, K=2 heads, O=32; temporal input unused)
//
// R10: compile fix only — __builtin_nontemporal_load requires a clang
// ext_vector pointer, not HIP's struct int4. The R9 A/B stands: (a) ~1.5TB/s
// HBM read-stream cap vs (b) structural coupling (1 block/CU, barrier-locked
// waves). adj2bytes v2 = perfectly-dense (1KB/instr), max-TLP (32 uncoupled
// waves/CU), 8 loads in flight/wave, NONTEMPORAL adj loads, LDS nibble
// transpose, 256B/wave coalesced store. gat_attn = proven byte-consuming form.
// If adj2bytes lands 11-15us -> structure was the cap. If ~43us -> read cap
// is the machine streaming roofline; declare ROOFLINE next round.
//
// prep_small — [0,64): Wh GEMM + e1/e2 node factors + whB B-frag store;
//              [64,169): LSTM/fc weight packing (B-frag layout).
// adj2bytes  — adj (64MB) -> mask bytes (2MB), pure stream, NT loads.
// gat_attn   — stage 16x512 mask bytes (stride-520 LDS rows, conflict-free);
//              exp-free masked-softmax+PV via mfma 16x16x32; combine 16 wave
//              partials; fused LSTM gates GEMM + nonlinearity + fc GEMM.

#define NN 4096

typedef __attribute__((ext_vector_type(8))) short bf16x8;
typedef __attribute__((ext_vector_type(4))) float f32x4;
typedef __attribute__((ext_vector_type(4))) int i32x4;

__device__ inline unsigned short bf_rne(float f) {
    unsigned u = __float_as_uint(f);
    u += 0x7fffu + ((u >> 16) & 1u);
    return (unsigned short)(u >> 16);
}

__device__ inline unsigned cvt_pk_bf16(float lo, float hi) {
    unsigned r;
    asm("v_cvt_pk_bf16_f32 %0, %1, %2" : "=v"(r) : "v"(lo), "v"(hi));
    return r;
}

__device__ inline float sigf(float x) { return 1.f / (1.f + __expf(-x)); }

__device__ inline unsigned nib4(const i32x4 a) {
    unsigned m = 0;
    m |= (a.x > 0) ? 1u : 0u;
    m |= (a.y > 0) ? 2u : 0u;
    m |= (a.z > 0) ? 4u : 0u;
    m |= (a.w > 0) ? 8u : 0u;
    return m;
}

// ---- adj (64MB int32) -> mask bytes ab[p*512 + (q>>3)] (2MB) ----
// Wave W covers int4 range [W*512, W*512+512) == output bytes [W*256, +256).
// Load o of wave W: lane l reads int4 (W*8+o)*64+l -> contiguous 1KB/instr,
// nontemporal (streamed once). Nibble transpose via 256B LDS per wave.
__global__ __launch_bounds__(256) void adj2bytes(
    const int* __restrict__ adj, unsigned char* __restrict__ ab)
{
    __shared__ unsigned nib_lds[4][64];
    const int tid = threadIdx.x;
    const int wave = tid >> 6, lane = tid & 63;
    const int W = blockIdx.x * 4 + wave;               // 8192 waves
    const i32x4* __restrict__ a4 = (const i32x4*)adj;
    i32x4 v[8];
#pragma unroll
    for (int o = 0; o < 8; ++o)
        v[o] = __builtin_nontemporal_load(&a4[(W * 8 + o) * 64 + lane]);
    unsigned nv = 0;
#pragma unroll
    for (int o = 0; o < 8; ++o)
        nv |= nib4(v[o]) << (4 * o);                   // nibble o = int4 o*64+lane
    nib_lds[wave][lane] = nv;
    __syncthreads();
    // byte B (0..255) = nibbles of local int4 2B (lo) and 2B+1 (hi):
    // lane = 2*(B&31), slot o = B>>5. Lane r emits bytes 4r..4r+3 as one u32.
    unsigned ov = 0;
#pragma unroll
    for (int i = 0; i < 4; ++i) {
        const int B = 4 * lane + i;
        const int o = B >> 5, j = B & 31;
        const unsigned lo = (nib_lds[wave][2 * j] >> (4 * o)) & 0xFu;
        const unsigned hi = (nib_lds[wave][2 * j + 1] >> (4 * o)) & 0xFu;
        ov |= (lo | (hi << 4)) << (8 * i);
    }
    ((unsigned*)ab)[W * 64 + lane] = ov;               // 256B/wave coalesced
}

__global__ __launch_bounds__(256) void prep_small(
    const float* __restrict__ X, const float* __restrict__ Wg,
    const float* __restrict__ a_src, const float* __restrict__ a_dst,
    const float* __restrict__ W_ih, const float* __restrict__ b_ih,
    const float* __restrict__ b_hh, const float* __restrict__ fc_W,
    unsigned short* __restrict__ whB, float* __restrict__ e1s,
    float* __restrict__ e2s, float* __restrict__ e1d, float* __restrict__ e2d,
    unsigned short* __restrict__ Wpk, unsigned short* __restrict__ fcb,
    float* __restrict__ biasg)
{
    __shared__ float X_lds[64][64];
    __shared__ float Wh_lds[64][65];
    __shared__ float spart[64][4][2];
    const int t = threadIdx.x;
    const int bid = blockIdx.x;

    if (bid >= 64) {
        // ---- weight packing ----
        const int idx = (bid - 64) * 256 + t;
        if (idx < 24576) {
            const int j = idx & 7, lane = (idx >> 3) & 63;
            const int k0 = (idx >> 9) & 3, tt = idx >> 11;
            const int jj = tt * 16 + (lane & 15);
            const int m = k0 * 32 + (lane >> 4) * 8 + j;
            const int sr = (jj < 64) ? jj : 64 + jj;        // skip dead f rows
            Wpk[idx] = bf_rne(W_ih[sr * 128 + m]);
        } else if (idx < 26624) {
            const int o = idx - 24576;                      // fc frag: 2 tiles
            const int j = o & 7, lane = (o >> 3) & 63;
            const int k0 = (o >> 9) & 1, tt = o >> 10;
            const int row = tt * 16 + (lane & 15);
            const int m = k0 * 32 + (lane >> 4) * 8 + j;
            fcb[o] = bf_rne(fc_W[row * 64 + m]);
        } else if (idx < 26816) {
            const int j = idx - 26624;
            const int sr = (j < 64) ? j : 64 + j;
            biasg[j] = b_ih[sr] + b_hh[sr];
        }
        return;
    }

    // ---- Wh GEMM + e-factors + whB B-frag store ----
    const int n0 = bid * 64;
#pragma unroll
    for (int i = 0; i < 16; ++i) {
        int idx = t + i * 256;
        X_lds[idx >> 6][idx & 63] = X[n0 * 64 + idx];
    }
    __syncthreads();
    const int h = t & 63, rg = t >> 6;
    for (int k = 0; k < 2; ++k) {
        float acc[16];
#pragma unroll
        for (int r = 0; r < 16; ++r) acc[r] = 0.f;
        for (int f0 = 0; f0 < 64; f0 += 4) {
            const float4 w4 = *(const float4*)&Wg[(k * 64 + h) * 64 + f0];
#pragma unroll
            for (int r = 0; r < 16; ++r) {
                const float4 x4 = *(const float4*)&X_lds[rg * 16 + r][f0];
                acc[r] += w4.x * x4.x + w4.y * x4.y + w4.z * x4.z + w4.w * x4.w;
            }
        }
        if (k) __syncthreads();
#pragma unroll
        for (int r = 0; r < 16; ++r) Wh_lds[rg * 16 + r][h] = acc[r];
        __syncthreads();
        {   // per-node logit terms (partial over 16 h each)
            const int r = t & 63, qa = t >> 6;
            float ps = 0.f, pd = 0.f;
#pragma unroll
            for (int i = 0; i < 16; ++i) {
                const int hh = qa * 16 + i;
                const float v = Wh_lds[r][hh];
                ps += v * a_src[k * 64 + hh];
                pd += v * a_dst[k * 64 + hh];
            }
            spart[r][qa][0] = ps;
            spart[r][qa][1] = pd;
        }
        {   // bf16 store in MFMA B-frag order:
            // flat = ((k*4+f)*128+qb)*512 + (qg*16+n)*8 + j
#pragma unroll
            for (int pid = t; pid < 512; pid += 256) {
                const int n = pid & 15, qg = (pid >> 4) & 3;
                const int qb_loc = (pid >> 6) & 1, f = pid >> 7;
                const int qb = (n0 >> 5) + qb_loc;
                unsigned pk[4];
#pragma unroll
                for (int i = 0; i < 4; ++i) {
                    const int r = qb_loc * 32 + qg * 8 + 2 * i;
                    unsigned lo = bf_rne(Wh_lds[r][f * 16 + n]);
                    unsigned hi = bf_rne(Wh_lds[r + 1][f * 16 + n]);
                    pk[i] = lo | (hi << 16);
                }
                uint4* dst = (uint4*)&whB[(((k * 4 + f) * 128 + qb) * 512) + (qg * 16 + n) * 8];
                *dst = make_uint4(pk[0], pk[1], pk[2], pk[3]);
            }
        }
        __syncthreads();
        if (t < 64) {
            float s0 = spart[t][0][0] + spart[t][1][0] + spart[t][2][0] + spart[t][3][0];
            float s1 = spart[t][0][1] + spart[t][1][1] + spart[t][2][1] + spart[t][3][1];
            e1s[k * NN + n0 + t] = __expf(s0);
            e2s[k * NN + n0 + t] = __expf(0.2f * s0);
            e1d[k * NN + n0 + t] = __expf(s1);
            e2d[k * NN + n0 + t] = __expf(0.2f * s1);
        }
    }
}

__global__ __launch_bounds__(1024) void gat_attn(
    const unsigned char* __restrict__ adjbytes,
    const unsigned short* __restrict__ whB,
    const float* __restrict__ e1s, const float* __restrict__ e2s,
    const float* __restrict__ e1d, const float* __restrict__ e2d,
    const unsigned short* __restrict__ Wpk, const unsigned short* __restrict__ fcb,
    const float* __restrict__ biasg, const float* __restrict__ fc_b,
    float* __restrict__ out)
{
    __shared__ float S_all[16][2][16][64];              // 128 KB wave partials
    __shared__ float z_all[16][2][16];                  // 2 KB
    __shared__ unsigned char byt_lds[16 * 520 + 8];     // 8.3 KB mask bytes
    // (row stride 520: dword idx = rloc*130 + c -> bank (2*rloc + c)&31,
    //  16 distinct banks, 4 qg lanes share one dword -> broadcast, no conflict)
    // post-combine aliases into dead S_all space:
    unsigned short* h_lds = (unsigned short*)&S_all[0][0][0][0];      // [16][136] bf16
    float* gate_lds = (float*)((char*)&S_all[0][0][0][0] + 4608);     // [3][16][68] f32

    const int tid = threadIdx.x;
    const int wave = tid >> 6, lane = tid & 63;
    const int rloc = lane & 15, qg = lane >> 4;
    const int p0 = blockIdx.x * 16;
    const int p = p0 + rloc;

    // ---- stage 16 rows x 512 mask bytes (coalesced u32 loads) ----
#pragma unroll
    for (int i = tid; i < 2048; i += 1024) {
        const int row = i >> 7, off = i & 127;
        *(unsigned*)&byt_lds[row * 520 + off * 4] =
            ((const unsigned*)adjbytes)[(p0 + row) * 128 + off];
    }
    __syncthreads();

    // per-lane row factors
    const float e1p0 = e1d[p], e2p0 = e2d[p];
    const float e1p1 = e1d[NN + p], e2p1 = e2d[NN + p];
    const unsigned short* __restrict__ whB_l = whB + lane * 8;

    f32x4 acc[2][4];
#pragma unroll
    for (int k = 0; k < 2; ++k)
#pragma unroll
        for (int f = 0; f < 4; ++f)
            acc[k][f] = (f32x4){0.f, 0.f, 0.f, 0.f};
    float z0 = 0.f, z1 = 0.f;

    const int qbase = wave * 256;   // each wave owns a 256-wide q slice
    for (int chunk = 0; chunk < 4; ++chunk) {
#pragma unroll
        for (int kk = 0; kk < 2; ++kk) {       // two K=32 steps per 64-q chunk
            const int q0 = qbase + chunk * 64 + kk * 32 + qg * 8;
            const int qb = wave * 8 + chunk * 2 + kk;
            const unsigned byte8 =
                byt_lds[rloc * 520 + wave * 32 + chunk * 8 + kk * 4 + qg];
            // q-side factors (L1/L2-hot broadcast arrays)
            const float4 qa0 = *(const float4*)(e1s + q0);
            const float4 qa1 = *(const float4*)(e1s + q0 + 4);
            const float4 qb0 = *(const float4*)(e2s + q0);
            const float4 qb1 = *(const float4*)(e2s + q0 + 4);
            const float4 qc0 = *(const float4*)(e1s + NN + q0);
            const float4 qc1 = *(const float4*)(e1s + NN + q0 + 4);
            const float4 qd0 = *(const float4*)(e2s + NN + q0);
            const float4 qd1 = *(const float4*)(e2s + NN + q0 + 4);
            const float q1v0[8] = {qa0.x, qa0.y, qa0.z, qa0.w, qa1.x, qa1.y, qa1.z, qa1.w};
            const float q2v0[8] = {qb0.x, qb0.y, qb0.z, qb0.w, qb1.x, qb1.y, qb1.z, qb1.w};
            const float q1v1[8] = {qc0.x, qc0.y, qc0.z, qc0.w, qc1.x, qc1.y, qc1.z, qc1.w};
            const float q2v1[8] = {qd0.x, qd0.y, qd0.z, qd0.w, qd1.x, qd1.y, qd1.z, qd1.w};
            float w0a[8], w1a[8];
#pragma unroll
            for (int j = 0; j < 8; ++j) {
                const bool on = (byte8 & (1u << j)) != 0u;
                // w = exp(lrelu(sd+ss)) ; pp=exp(sd+ss) ; pp>1 <=> sd+ss>0
                const float pp0 = e1p0 * q1v0[j];
                float w0 = pp0 > 1.f ? pp0 : e2p0 * q2v0[j];
                w0 = on ? w0 : 0.f;
                z0 += w0;
                w0a[j] = w0;
                const float pp1 = e1p1 * q1v1[j];
                float w1 = pp1 > 1.f ? pp1 : e2p1 * q2v1[j];
                w1 = on ? w1 : 0.f;
                z1 += w1;
                w1a[j] = w1;
            }
            union { bf16x8 v; unsigned w[4]; } fa0, fa1;
#pragma unroll
            for (int i = 0; i < 4; ++i) {
                fa0.w[i] = cvt_pk_bf16(w0a[2 * i], w0a[2 * i + 1]);
                fa1.w[i] = cvt_pk_bf16(w1a[2 * i], w1a[2 * i + 1]);
            }
#pragma unroll
            for (int f = 0; f < 4; ++f) {
                const bf16x8 b0 = *(const bf16x8*)(whB_l + ((f * 128 + qb) << 9));
                acc[0][f] = __builtin_amdgcn_mfma_f32_16x16x32_bf16(fa0.v, b0, acc[0][f], 0, 0, 0);
                const bf16x8 b1 = *(const bf16x8*)(whB_l + (((4 + f) * 128 + qb) << 9));
                acc[1][f] = __builtin_amdgcn_mfma_f32_16x16x32_bf16(fa1.v, b1, acc[1][f], 0, 0, 0);
            }
        }
    }
    // z: sum the 4 q-groups (lanes l, l^16, l^32, l^48 share a row)
    z0 += __shfl_xor(z0, 16); z0 += __shfl_xor(z0, 32);
    z1 += __shfl_xor(z1, 16); z1 += __shfl_xor(z1, 32);
    if (lane < 16) { z_all[wave][0][lane] = z0; z_all[wave][1][lane] = z1; }
    // D-frag layout: row=(l>>4)*4+j, col=l&15
#pragma unroll
    for (int k = 0; k < 2; ++k)
#pragma unroll
        for (int f = 0; f < 4; ++f)
#pragma unroll
            for (int j = 0; j < 4; ++j)
                S_all[wave][k][qg * 4 + j][f * 16 + rloc] = acc[k][f][j];
    __syncthreads();
    // combine 16 wave-partials, normalize, elu -> registers
    float vreg[2]; int vk[2], vr[2], vh[2];
#pragma unroll
    for (int i = 0; i < 2; ++i) {
        const int idx = tid + i * 1024;
        const int k = idx >> 10, rr = (idx >> 6) & 15, hh = idx & 63;
        float s = 0.f, z = 0.f;
#pragma unroll
        for (int w = 0; w < 16; ++w) {
            s += S_all[w][k][rr][hh];
            z += z_all[w][k][rr];
        }
        float v = s / z;
        vreg[i] = v > 0.f ? v : expm1f(v);
        vk[i] = k; vr[i] = rr; vh[i] = hh;
    }
    __syncthreads();    // all S_all reads done; safe to reuse as h_lds/gate_lds
    // h tile bf16 [node][k*64+h], padded row 136 (272B, 16B-aligned rows)
#pragma unroll
    for (int i = 0; i < 2; ++i)
        h_lds[vr[i] * 136 + vk[i] * 64 + vh[i]] = bf_rne(vreg[i]);
    __syncthreads();

    // ---- fused LSTM gates GEMM: 12 waves, one 16-col gate tile each ----
    const int c2 = lane & 15, g4 = lane >> 4;
    if (wave < 12) {
        const int t = wave;
        f32x4 ga = (f32x4){0.f, 0.f, 0.f, 0.f};
#pragma unroll
        for (int k0 = 0; k0 < 4; ++k0) {
            const bf16x8 a = *(const bf16x8*)&h_lds[c2 * 136 + k0 * 32 + g4 * 8];
            const bf16x8 b = *(const bf16x8*)&Wpk[((t * 4 + k0) * 64 + lane) * 8];
            ga = __builtin_amdgcn_mfma_f32_16x16x32_bf16(a, b, ga, 0, 0, 0);
        }
        const float bb = biasg[t * 16 + c2];
#pragma unroll
        for (int j = 0; j < 4; ++j)
            gate_lds[(t >> 2) * 1088 + (g4 * 4 + j) * 68 + (t & 3) * 16 + c2] = ga[j] + bb;
    }
    __syncthreads();
    // ---- LSTM nonlinearity: ht = sig(o)*tanh(sig(i)*tanh(g)) ----
    {
        const int n = tid >> 6, hh = tid & 63;
        const float iv = gate_lds[n * 68 + hh];
        const float gv = gate_lds[1088 + n * 68 + hh];
        const float ov = gate_lds[2176 + n * 68 + hh];
        const float cv = sigf(iv) * tanhf(gv);
        const float htv = sigf(ov) * tanhf(cv);
        __syncthreads();
        h_lds[n * 136 + hh] = bf_rne(htv);   // reuse h_lds (gates consumed h)
    }
    __syncthreads();
    // ---- fc GEMM: waves 0,1 -> out[16 nodes][32] ----
    if (wave < 2) {
        const int t2 = wave;
        f32x4 fa = (f32x4){0.f, 0.f, 0.f, 0.f};
#pragma unroll
        for (int k0 = 0; k0 < 2; ++k0) {
            const bf16x8 a = *(const bf16x8*)&h_lds[c2 * 136 + k0 * 32 + g4 * 8];
            const bf16x8 b = *(const bf16x8*)&fcb[((t2 * 2 + k0) * 64 + lane) * 8];
            fa = __builtin_amdgcn_mfma_f32_16x16x32_bf16(a, b, fa, 0, 0, 0);
        }
        const float fb = fc_b[t2 * 16 + c2];
#pragma unroll
        for (int j = 0; j < 4; ++j)
            out[(p0 + g4 * 4 + j) * 32 + t2 * 16 + c2] = fa[j] + fb;
    }
}

extern "C" void kernel_launch(void* const* d_in, const int* in_sizes, int n_in,
                              void* d_out, int out_size, void* d_ws, size_t ws_size,
                              hipStream_t stream) {
    const float* X     = (const float*)d_in[0];
    const int*   adj   = (const int*)d_in[1];
    // d_in[2] temporal_features: unused by the reference
    const float* Wg    = (const float*)d_in[3];
    const float* a_src = (const float*)d_in[4];
    const float* a_dst = (const float*)d_in[5];
    const float* W_ih  = (const float*)d_in[6];
    // d_in[7] W_hh: unused (h0 == 0)
    const float* b_ih  = (const float*)d_in[8];
    const float* b_hh  = (const float*)d_in[9];
    const float* fc_W  = (const float*)d_in[10];
    const float* fc_b  = (const float*)d_in[11];
    float* out = (float*)d_out;

    char* ws = (char*)d_ws;
    unsigned short* whB = (unsigned short*)ws;                       // 1 MB
    float* e1s = (float*)(ws + (1 << 20));                           // 32 KB
    float* e2s = (float*)(ws + (1 << 20) + (32 << 10));              // 32 KB
    float* e1d = (float*)(ws + (1 << 20) + (64 << 10));              // 32 KB
    float* e2d = (float*)(ws + (1 << 20) + (96 << 10));              // 32 KB
    unsigned char* adjbytes = (unsigned char*)(ws + (1 << 20) + (128 << 10)); // 2 MB
    char* ws2 = ws + (3 << 20) + (128 << 10);
    unsigned short* Wpk = (unsigned short*)ws2;                      // 48 KB
    unsigned short* fcb = (unsigned short*)(ws2 + (48 << 10));       // 4 KB
    float* biasg = (float*)(ws2 + (52 << 10));                       // 768 B

    hipLaunchKernelGGL(adj2bytes, dim3(2048), dim3(256), 0, stream,
                       adj, adjbytes);
    hipLaunchKernelGGL(prep_small, dim3(169), dim3(256), 0, stream,
                       X, Wg, a_src, a_dst, W_ih, b_ih, b_hh, fc_W,
                       whB, e1s, e2s, e1d, e2d, Wpk, fcb, biasg);
    hipLaunchKernelGGL(gat_attn, dim3(256), dim3(1024), 0, stream,
                       adjbytes, whB, e1s, e2s, e1d, e2d, Wpk, fcb, biasg, fc_b, out);
}

// Round 12
// 54.646 us; speedup vs baseline: 1.0995x; 1.0350x over previous
//
#include <hip/hip_runtime.h>

// SpatioTemporalGAT  (N=4096, F=64, H=64, K=2 heads, O=32; temporal input unused)
//
// R11 verdict: 8 structurally different adj passes (ballot, byte-stream,
// fused, dense+NT, max-TLP) all read the 64MB adj input at ~1.5-1.7 TB/s
// (38-45us) while ws writes hit 6.8 TB/s -- the cap is a property of reading
// this input buffer, not of kernel structure. Harness determinism forbids
// caching the compressed mask across calls, so ~40us adj read is the floor.
// Plan: hide ALL other work under it. R8's fused kernel already ran
// adj+attn+LSTM in 43.4us (compute hidden under stream); the remaining slack
// was prep_small (~10us: 64-block GEMM left 192 CUs idle).
//
// prep_parallel — [0,256): Wh GEMM re-tiled to 16 nodes/block (all CUs busy,
//                 fully-unrolled f0 loop -> 32 hoisted Wg loads, deep MLP);
//                 e1/e2 node factors + whB B-frag store.
//                 [256,361): LSTM/fc weight packing (B-frag layout).
// gat_attn      — R8's fused chunk-pipelined {NT adj load || masked-softmax+PV
//                 mfma 16x16x32}; exp-free hot loop (w = pp>1 ? e1p*e1q :
//                 e2p*e2q); combine 16 wave partials; fused LSTM gates GEMM +
//                 nonlinearity + fc GEMM epilogue.

#define NN 4096

typedef __attribute__((ext_vector_type(8))) short bf16x8;
typedef __attribute__((ext_vector_type(4))) float f32x4;
typedef __attribute__((ext_vector_type(4))) int i32x4;

__device__ inline unsigned short bf_rne(float f) {
    unsigned u = __float_as_uint(f);
    u += 0x7fffu + ((u >> 16) & 1u);
    return (unsigned short)(u >> 16);
}

__device__ inline unsigned cvt_pk_bf16(float lo, float hi) {
    unsigned r;
    asm("v_cvt_pk_bf16_f32 %0, %1, %2" : "=v"(r) : "v"(lo), "v"(hi));
    return r;
}

__device__ inline float sigf(float x) { return 1.f / (1.f + __expf(-x)); }

__device__ inline unsigned pack16(const i32x4 a, const i32x4 b,
                                  const i32x4 c, const i32x4 d) {
    unsigned m = 0;
    m |= (a.x > 0) ? 0x0001u : 0u; m |= (a.y > 0) ? 0x0002u : 0u;
    m |= (a.z > 0) ? 0x0004u : 0u; m |= (a.w > 0) ? 0x0008u : 0u;
    m |= (b.x > 0) ? 0x0010u : 0u; m |= (b.y > 0) ? 0x0020u : 0u;
    m |= (b.z > 0) ? 0x0040u : 0u; m |= (b.w > 0) ? 0x0080u : 0u;
    m |= (c.x > 0) ? 0x0100u : 0u; m |= (c.y > 0) ? 0x0200u : 0u;
    m |= (c.z > 0) ? 0x0400u : 0u; m |= (c.w > 0) ? 0x0800u : 0u;
    m |= (d.x > 0) ? 0x1000u : 0u; m |= (d.y > 0) ? 0x2000u : 0u;
    m |= (d.z > 0) ? 0x4000u : 0u; m |= (d.w > 0) ? 0x8000u : 0u;
    return m;
}

__global__ __launch_bounds__(256) void prep_parallel(
    const float* __restrict__ X, const float* __restrict__ Wg,
    const float* __restrict__ a_src, const float* __restrict__ a_dst,
    const float* __restrict__ W_ih, const float* __restrict__ b_ih,
    const float* __restrict__ b_hh, const float* __restrict__ fc_W,
    unsigned short* __restrict__ whB, float* __restrict__ e1s,
    float* __restrict__ e2s, float* __restrict__ e1d, float* __restrict__ e2d,
    unsigned short* __restrict__ Wpk, unsigned short* __restrict__ fcb,
    float* __restrict__ biasg)
{
    __shared__ float X_lds[16][64];
    __shared__ float Wh_lds[2][16][68];
    __shared__ float spart[32][8][2];
    const int t = threadIdx.x;
    const int bid = blockIdx.x;

    if (bid >= 256) {
        // ---- weight packing ----
        const int idx = (bid - 256) * 256 + t;
        if (idx < 24576) {
            const int j = idx & 7, lane = (idx >> 3) & 63;
            const int k0 = (idx >> 9) & 3, tt = idx >> 11;
            const int jj = tt * 16 + (lane & 15);
            const int m = k0 * 32 + (lane >> 4) * 8 + j;
            const int sr = (jj < 64) ? jj : 64 + jj;        // skip dead f rows
            Wpk[idx] = bf_rne(W_ih[sr * 128 + m]);
        } else if (idx < 26624) {
            const int o = idx - 24576;                      // fc frag: 2 tiles
            const int j = o & 7, lane = (o >> 3) & 63;
            const int k0 = (o >> 9) & 1, tt = o >> 10;
            const int row = tt * 16 + (lane & 15);
            const int m = k0 * 32 + (lane >> 4) * 8 + j;
            fcb[o] = bf_rne(fc_W[row * 64 + m]);
        } else if (idx < 26816) {
            const int j = idx - 26624;
            const int sr = (j < 64) ? j : 64 + j;
            biasg[j] = b_ih[sr] + b_hh[sr];
        }
        return;
    }

    // ---- Wh GEMM: 16 nodes per block, all 256 CUs busy ----
    const int n0 = bid * 16;
    {
        const float4 x4 = *(const float4*)&X[(long)n0 * 64 + t * 4];
        *(float4*)&X_lds[t >> 4][(t & 15) * 4] = x4;
    }
    __syncthreads();
    const int h = t & 63, grp = t >> 6;     // grp == wave; X row broadcast/wave
    float acc0[4] = {0.f, 0.f, 0.f, 0.f};
    float acc1[4] = {0.f, 0.f, 0.f, 0.f};
#pragma unroll
    for (int f0 = 0; f0 < 64; f0 += 4) {    // fully unrolled: 32 hoisted loads
        const float4 wa = *(const float4*)&Wg[h * 64 + f0];
        const float4 wb = *(const float4*)&Wg[(64 + h) * 64 + f0];
#pragma unroll
        for (int r = 0; r < 4; ++r) {
            const float4 x4 = *(const float4*)&X_lds[grp * 4 + r][f0];
            acc0[r] += wa.x * x4.x + wa.y * x4.y + wa.z * x4.z + wa.w * x4.w;
            acc1[r] += wb.x * x4.x + wb.y * x4.y + wb.z * x4.z + wb.w * x4.w;
        }
    }
#pragma unroll
    for (int r = 0; r < 4; ++r) {
        Wh_lds[0][grp * 4 + r][h] = acc0[r];
        Wh_lds[1][grp * 4 + r][h] = acc1[r];
    }
    __syncthreads();
    {   // logit-term partials: (k,node) x 8 h-groups
        const int r2 = t & 31, qa = t >> 5;
        const int k = r2 >> 4, nd = r2 & 15;
        float ps = 0.f, pd = 0.f;
#pragma unroll
        for (int i = 0; i < 8; ++i) {
            const int hh = qa * 8 + i;
            const float v = Wh_lds[k][nd][hh];
            ps += v * a_src[k * 64 + hh];
            pd += v * a_dst[k * 64 + hh];
        }
        spart[r2][qa][0] = ps;
        spart[r2][qa][1] = pd;
    }
    // whB B-frag store: element (k,h,q): f=h>>4, n=h&15, qb=q>>5, qg=(q>>3)&3,
    // j=q&7; flat = ((k*4+f)*128+qb)*512 + (qg*16+n)*8 + j. Pack 2 bf16/u32.
    {
        const int qb = n0 >> 5;
        const int qgbase = (n0 & 31) >> 3;
#pragma unroll
        for (int it = 0; it < 4; ++it) {
            const int pid = t + it * 256;           // 0..1023
            const int j2 = pid & 3, qgl = (pid >> 2) & 1;
            const int n = (pid >> 3) & 15, f = (pid >> 7) & 3, k = pid >> 9;
            const int i0 = qgl * 8 + j2 * 2;
            const unsigned lo = bf_rne(Wh_lds[k][i0][f * 16 + n]);
            const unsigned hi = bf_rne(Wh_lds[k][i0 + 1][f * 16 + n]);
            unsigned* dst = (unsigned*)&whB[(((k * 4 + f) * 128 + qb) * 512)
                                            + ((qgbase + qgl) * 16 + n) * 8 + j2 * 2];
            *dst = lo | (hi << 16);
        }
    }
    __syncthreads();
    if (t < 32) {
        const int k = t >> 4, nd = t & 15;
        float s0 = 0.f, s1 = 0.f;
#pragma unroll
        for (int qa = 0; qa < 8; ++qa) {
            s0 += spart[t][qa][0];
            s1 += spart[t][qa][1];
        }
        e1s[k * NN + n0 + nd] = __expf(s0);
        e2s[k * NN + n0 + nd] = __expf(0.2f * s0);
        e1d[k * NN + n0 + nd] = __expf(s1);
        e2d[k * NN + n0 + nd] = __expf(0.2f * s1);
    }
}

__global__ __launch_bounds__(1024) void gat_attn(
    const int* __restrict__ adj,
    const unsigned short* __restrict__ whB,
    const float* __restrict__ e1s, const float* __restrict__ e2s,
    const float* __restrict__ e1d, const float* __restrict__ e2d,
    const unsigned short* __restrict__ Wpk, const unsigned short* __restrict__ fcb,
    const float* __restrict__ biasg, const float* __restrict__ fc_b,
    float* __restrict__ out)
{
    __shared__ float S_all[16][2][16][64];              // 128 KB wave partials
    __shared__ float z_all[16][2][16];                  // 2 KB
    __shared__ unsigned short msk_lds[2][16][66];       // 4.1 KB dbuf mask tile
    // post-combine aliases into dead S_all space:
    unsigned short* h_lds = (unsigned short*)&S_all[0][0][0][0];      // [16][136] bf16
    float* gate_lds = (float*)((char*)&S_all[0][0][0][0] + 4608);     // [3][16][68] f32

    const int tid = threadIdx.x;
    const int wave = tid >> 6, lane = tid & 63;
    const int rloc = lane & 15, qg = lane >> 4;
    const int p0 = blockIdx.x * 16;
    const int p = p0 + rloc;

    // wave w streams adj row p0+w; lane l covers q in [c*1024+16l, +16)
    const i32x4* __restrict__ arow = (const i32x4*)(adj + (long)(p0 + wave) * NN);

    // per-lane row factors
    const float e1p0 = e1d[p], e2p0 = e2d[p];
    const float e1p1 = e1d[NN + p], e2p1 = e2d[NN + p];
    const unsigned short* __restrict__ whB_l = whB + lane * 8;

    f32x4 acc[2][4];
#pragma unroll
    for (int k = 0; k < 2; ++k)
#pragma unroll
        for (int f = 0; f < 4; ++f)
            acc[k][f] = (f32x4){0.f, 0.f, 0.f, 0.f};
    float z0 = 0.f, z1 = 0.f;

    // ---- prologue: stage chunk 0 masks ----
    {
        const i32x4 a0 = __builtin_nontemporal_load(&arow[lane * 4 + 0]);
        const i32x4 a1 = __builtin_nontemporal_load(&arow[lane * 4 + 1]);
        const i32x4 a2 = __builtin_nontemporal_load(&arow[lane * 4 + 2]);
        const i32x4 a3 = __builtin_nontemporal_load(&arow[lane * 4 + 3]);
        msk_lds[0][wave][lane] = (unsigned short)pack16(a0, a1, a2, a3);
    }
    __syncthreads();

#pragma unroll
    for (int c = 0; c < 4; ++c) {
        // issue next chunk's adj loads before compute (hides under MFMA/VALU)
        i32x4 n0v, n1v, n2v, n3v;
        if (c < 3) {
            const int base = (c + 1) * 256 + lane * 4;
            n0v = __builtin_nontemporal_load(&arow[base + 0]);
            n1v = __builtin_nontemporal_load(&arow[base + 1]);
            n2v = __builtin_nontemporal_load(&arow[base + 2]);
            n3v = __builtin_nontemporal_load(&arow[base + 3]);
        }
        // ---- compute chunk c: wave handles q in [c*1024 + wave*64, +64) ----
#pragma unroll
        for (int kk = 0; kk < 2; ++kk) {
            const int q0 = c * 1024 + wave * 64 + kk * 32 + qg * 8;
            const int qb = c * 32 + wave * 2 + kk;
            const unsigned mm = msk_lds[c & 1][rloc][wave * 4 + kk * 2 + (qg >> 1)];
            const unsigned byte8 = (mm >> ((qg & 1) * 8)) & 0xffu;
            // q-side factors (L1/L2-hot broadcast arrays)
            const float4 qa0 = *(const float4*)(e1s + q0);
            const float4 qa1 = *(const float4*)(e1s + q0 + 4);
            const float4 qb0 = *(const float4*)(e2s + q0);
            const float4 qb1 = *(const float4*)(e2s + q0 + 4);
            const float4 qc0 = *(const float4*)(e1s + NN + q0);
            const float4 qc1 = *(const float4*)(e1s + NN + q0 + 4);
            const float4 qd0 = *(const float4*)(e2s + NN + q0);
            const float4 qd1 = *(const float4*)(e2s + NN + q0 + 4);
            const float q1v0[8] = {qa0.x, qa0.y, qa0.z, qa0.w, qa1.x, qa1.y, qa1.z, qa1.w};
            const float q2v0[8] = {qb0.x, qb0.y, qb0.z, qb0.w, qb1.x, qb1.y, qb1.z, qb1.w};
            const float q1v1[8] = {qc0.x, qc0.y, qc0.z, qc0.w, qc1.x, qc1.y, qc1.z, qc1.w};
            const float q2v1[8] = {qd0.x, qd0.y, qd0.z, qd0.w, qd1.x, qd1.y, qd1.z, qd1.w};
            float w0a[8], w1a[8];
#pragma unroll
            for (int j = 0; j < 8; ++j) {
                const bool on = (byte8 & (1u << j)) != 0u;
                // w = exp(lrelu(sd+ss)) ; pp=exp(sd+ss) ; pp>1 <=> sd+ss>0
                const float pp0 = e1p0 * q1v0[j];
                float w0 = pp0 > 1.f ? pp0 : e2p0 * q2v0[j];
                w0 = on ? w0 : 0.f;
                z0 += w0;
                w0a[j] = w0;
                const float pp1 = e1p1 * q1v1[j];
                float w1 = pp1 > 1.f ? pp1 : e2p1 * q2v1[j];
                w1 = on ? w1 : 0.f;
                z1 += w1;
                w1a[j] = w1;
            }
            union { bf16x8 v; unsigned w[4]; } fa0, fa1;
#pragma unroll
            for (int i = 0; i < 4; ++i) {
                fa0.w[i] = cvt_pk_bf16(w0a[2 * i], w0a[2 * i + 1]);
                fa1.w[i] = cvt_pk_bf16(w1a[2 * i], w1a[2 * i + 1]);
            }
#pragma unroll
            for (int f = 0; f < 4; ++f) {
                const bf16x8 b0 = *(const bf16x8*)(whB_l + ((f * 128 + qb) << 9));
                acc[0][f] = __builtin_amdgcn_mfma_f32_16x16x32_bf16(fa0.v, b0, acc[0][f], 0, 0, 0);
                const bf16x8 b1 = *(const bf16x8*)(whB_l + (((4 + f) * 128 + qb) << 9));
                acc[1][f] = __builtin_amdgcn_mfma_f32_16x16x32_bf16(fa1.v, b1, acc[1][f], 0, 0, 0);
            }
        }
        if (c < 3) {
            // buffer (c+1)&1 last read in chunk c-1, fenced by that barrier
            msk_lds[(c + 1) & 1][wave][lane] =
                (unsigned short)pack16(n0v, n1v, n2v, n3v);
            __syncthreads();
        }
    }
    // z: sum the 4 q-groups (lanes l, l^16, l^32, l^48 share a row)
    z0 += __shfl_xor(z0, 16); z0 += __shfl_xor(z0, 32);
    z1 += __shfl_xor(z1, 16); z1 += __shfl_xor(z1, 32);
    if (lane < 16) { z_all[wave][0][lane] = z0; z_all[wave][1][lane] = z1; }
    // D-frag layout: row=(l>>4)*4+j, col=l&15
#pragma unroll
    for (int k = 0; k < 2; ++k)
#pragma unroll
        for (int f = 0; f < 4; ++f)
#pragma unroll
            for (int j = 0; j < 4; ++j)
                S_all[wave][k][qg * 4 + j][f * 16 + rloc] = acc[k][f][j];
    __syncthreads();
    // combine 16 wave-partials, normalize, elu -> registers
    float vreg[2]; int vk[2], vr[2], vh[2];
#pragma unroll
    for (int i = 0; i < 2; ++i) {
        const int idx = tid + i * 1024;
        const int k = idx >> 10, rr = (idx >> 6) & 15, hh = idx & 63;
        float s = 0.f, z = 0.f;
#pragma unroll
        for (int w = 0; w < 16; ++w) {
            s += S_all[w][k][rr][hh];
            z += z_all[w][k][rr];
        }
        float v = s / z;
        vreg[i] = v > 0.f ? v : expm1f(v);
        vk[i] = k; vr[i] = rr; vh[i] = hh;
    }
    __syncthreads();    // all S_all reads done; safe to reuse as h_lds/gate_lds
    // h tile bf16 [node][k*64+h], padded row 136 (272B, 16B-aligned rows)
#pragma unroll
    for (int i = 0; i < 2; ++i)
        h_lds[vr[i] * 136 + vk[i] * 64 + vh[i]] = bf_rne(vreg[i]);
    __syncthreads();

    // ---- fused LSTM gates GEMM: 12 waves, one 16-col gate tile each ----
    const int c2 = lane & 15, g4 = lane >> 4;
    if (wave < 12) {
        const int t = wave;
        f32x4 ga = (f32x4){0.f, 0.f, 0.f, 0.f};
#pragma unroll
        for (int k0 = 0; k0 < 4; ++k0) {
            const bf16x8 a = *(const bf16x8*)&h_lds[c2 * 136 + k0 * 32 + g4 * 8];
            const bf16x8 b = *(const bf16x8*)&Wpk[((t * 4 + k0) * 64 + lane) * 8];
            ga = __builtin_amdgcn_mfma_f32_16x16x32_bf16(a, b, ga, 0, 0, 0);
        }
        const float bb = biasg[t * 16 + c2];
#pragma unroll
        for (int j = 0; j < 4; ++j)
            gate_lds[(t >> 2) * 1088 + (g4 * 4 + j) * 68 + (t & 3) * 16 + c2] = ga[j] + bb;
    }
    __syncthreads();
    // ---- LSTM nonlinearity: ht = sig(o)*tanh(sig(i)*tanh(g)) ----
    {
        const int n = tid >> 6, hh = tid & 63;
        const float iv = gate_lds[n * 68 + hh];
        const float gv = gate_lds[1088 + n * 68 + hh];
        const float ov = gate_lds[2176 + n * 68 + hh];
        const float cv = sigf(iv) * tanhf(gv);
        const float htv = sigf(ov) * tanhf(cv);
        __syncthreads();
        h_lds[n * 136 + hh] = bf_rne(htv);   // reuse h_lds (gates consumed h)
    }
    __syncthreads();
    // ---- fc GEMM: waves 0,1 -> out[16 nodes][32] ----
    if (wave < 2) {
        const int t2 = wave;
        f32x4 fa = (f32x4){0.f, 0.f, 0.f, 0.f};
#pragma unroll
        for (int k0 = 0; k0 < 2; ++k0) {
            const bf16x8 a = *(const bf16x8*)&h_lds[c2 * 136 + k0 * 32 + g4 * 8];
            const bf16x8 b = *(const bf16x8*)&fcb[((t2 * 2 + k0) * 64 + lane) * 8];
            fa = __builtin_amdgcn_mfma_f32_16x16x32_bf16(a, b, fa, 0, 0, 0);
        }
        const float fb = fc_b[t2 * 16 + c2];
#pragma unroll
        for (int j = 0; j < 4; ++j)
            out[(p0 + g4 * 4 + j) * 32 + t2 * 16 + c2] = fa[j] + fb;
    }
}

extern "C" void kernel_launch(void* const* d_in, const int* in_sizes, int n_in,
                              void* d_out, int out_size, void* d_ws, size_t ws_size,
                              hipStream_t stream) {
    const float* X     = (const float*)d_in[0];
    const int*   adj   = (const int*)d_in[1];
    // d_in[2] temporal_features: unused by the reference
    const float* Wg    = (const float*)d_in[3];
    const float* a_src = (const float*)d_in[4];
    const float* a_dst = (const float*)d_in[5];
    const float* W_ih  = (const float*)d_in[6];
    // d_in[7] W_hh: unused (h0 == 0)
    const float* b_ih  = (const float*)d_in[8];
    const float* b_hh  = (const float*)d_in[9];
    const float* fc_W  = (const float*)d_in[10];
    const float* fc_b  = (const float*)d_in[11];
    float* out = (float*)d_out;

    char* ws = (char*)d_ws;
    unsigned short* whB = (unsigned short*)ws;                       // 1 MB
    float* e1s = (float*)(ws + (1 << 20));                           // 32 KB
    float* e2s = (float*)(ws + (1 << 20) + (32 << 10));              // 32 KB
    float* e1d = (float*)(ws + (1 << 20) + (64 << 10));              // 32 KB
    float* e2d = (float*)(ws + (1 << 20) + (96 << 10));              // 32 KB
    char* ws2 = ws + (1 << 20) + (128 << 10);
    unsigned short* Wpk = (unsigned short*)ws2;                      // 48 KB
    unsigned short* fcb = (unsigned short*)(ws2 + (48 << 10));       // 4 KB
    float* biasg = (float*)(ws2 + (52 << 10));                       // 768 B

    hipLaunchKernelGGL(prep_parallel, dim3(361), dim3(256), 0, stream,
                       X, Wg, a_src, a_dst, W_ih, b_ih, b_hh, fc_W,
                       whB, e1s, e2s, e1d, e2d, Wpk, fcb, biasg);
    hipLaunchKernelGGL(gat_attn, dim3(256), dim3(1024), 0, stream,
                       adj, whB, e1s, e2s, e1d, e2d, Wpk, fcb, biasg, fc_b, out);
}

// Round 13
// 53.070 us; speedup vs baseline: 1.1322x; 1.0297x over previous
//
#include <hip/hip_runtime.h>

// SpatioTemporalGAT  (N=4096, F=64, H=64, K=2 heads, O=32; temporal input unused)
//
// R12 lesson: NT hints on the adj stream SUPPRESSED L3 retention (adj is 64MB
// vs 256MB L3; ~25MB stayed resident across replays -> FETCH 37.5MB < 64MB),
// costing +4-5us. Reverted to plain cacheable loads (R8's measured 43.4us
// path). Final accounting: 9 structurally diverse adj passes all read this
// 64MB input at 1.5-1.7 TB/s (pattern/TLP/coupling-independent) with only
// ~37MB from HBM -- a per-CU outstanding-miss x latency cap (4096 lines/CU x
// ~900cy / ~40 MSHR = ~38us), not addressable at HIP level. The fused kernel
// hides ALL compute (masked-softmax+PV, LSTM, fc) under that stream.
//
// prep_parallel — [0,256): Wh GEMM 16 nodes/block (all CUs); e1/e2 factors +
//                 whB B-frag store. [256,361): LSTM/fc weight packing.
// gat_attn      — fused chunk-pipelined {adj load || masked-softmax+PV mfma};
//                 exp-free hot loop (w = pp>1 ? e1p*e1q : e2p*e2q); combine
//                 16 wave partials; fused LSTM gates GEMM + nonlin + fc GEMM.

#define NN 4096

typedef __attribute__((ext_vector_type(8))) short bf16x8;
typedef __attribute__((ext_vector_type(4))) float f32x4;
typedef __attribute__((ext_vector_type(4))) int i32x4;

__device__ inline unsigned short bf_rne(float f) {
    unsigned u = __float_as_uint(f);
    u += 0x7fffu + ((u >> 16) & 1u);
    return (unsigned short)(u >> 16);
}

__device__ inline unsigned cvt_pk_bf16(float lo, float hi) {
    unsigned r;
    asm("v_cvt_pk_bf16_f32 %0, %1, %2" : "=v"(r) : "v"(lo), "v"(hi));
    return r;
}

__device__ inline float sigf(float x) { return 1.f / (1.f + __expf(-x)); }

__device__ inline unsigned pack16(const i32x4 a, const i32x4 b,
                                  const i32x4 c, const i32x4 d) {
    unsigned m = 0;
    m |= (a.x > 0) ? 0x0001u : 0u; m |= (a.y > 0) ? 0x0002u : 0u;
    m |= (a.z > 0) ? 0x0004u : 0u; m |= (a.w > 0) ? 0x0008u : 0u;
    m |= (b.x > 0) ? 0x0010u : 0u; m |= (b.y > 0) ? 0x0020u : 0u;
    m |= (b.z > 0) ? 0x0040u : 0u; m |= (b.w > 0) ? 0x0080u : 0u;
    m |= (c.x > 0) ? 0x0100u : 0u; m |= (c.y > 0) ? 0x0200u : 0u;
    m |= (c.z > 0) ? 0x0400u : 0u; m |= (c.w > 0) ? 0x0800u : 0u;
    m |= (d.x > 0) ? 0x1000u : 0u; m |= (d.y > 0) ? 0x2000u : 0u;
    m |= (d.z > 0) ? 0x4000u : 0u; m |= (d.w > 0) ? 0x8000u : 0u;
    return m;
}

__global__ __launch_bounds__(256) void prep_parallel(
    const float* __restrict__ X, const float* __restrict__ Wg,
    const float* __restrict__ a_src, const float* __restrict__ a_dst,
    const float* __restrict__ W_ih, const float* __restrict__ b_ih,
    const float* __restrict__ b_hh, const float* __restrict__ fc_W,
    unsigned short* __restrict__ whB, float* __restrict__ e1s,
    float* __restrict__ e2s, float* __restrict__ e1d, float* __restrict__ e2d,
    unsigned short* __restrict__ Wpk, unsigned short* __restrict__ fcb,
    float* __restrict__ biasg)
{
    __shared__ float X_lds[16][64];
    __shared__ float Wh_lds[2][16][68];
    __shared__ float spart[32][8][2];
    const int t = threadIdx.x;
    const int bid = blockIdx.x;

    if (bid >= 256) {
        // ---- weight packing ----
        const int idx = (bid - 256) * 256 + t;
        if (idx < 24576) {
            const int j = idx & 7, lane = (idx >> 3) & 63;
            const int k0 = (idx >> 9) & 3, tt = idx >> 11;
            const int jj = tt * 16 + (lane & 15);
            const int m = k0 * 32 + (lane >> 4) * 8 + j;
            const int sr = (jj < 64) ? jj : 64 + jj;        // skip dead f rows
            Wpk[idx] = bf_rne(W_ih[sr * 128 + m]);
        } else if (idx < 26624) {
            const int o = idx - 24576;                      // fc frag: 2 tiles
            const int j = o & 7, lane = (o >> 3) & 63;
            const int k0 = (o >> 9) & 1, tt = o >> 10;
            const int row = tt * 16 + (lane & 15);
            const int m = k0 * 32 + (lane >> 4) * 8 + j;
            fcb[o] = bf_rne(fc_W[row * 64 + m]);
        } else if (idx < 26816) {
            const int j = idx - 26624;
            const int sr = (j < 64) ? j : 64 + j;
            biasg[j] = b_ih[sr] + b_hh[sr];
        }
        return;
    }

    // ---- Wh GEMM: 16 nodes per block, all 256 CUs busy ----
    const int n0 = bid * 16;
    {
        const float4 x4 = *(const float4*)&X[(long)n0 * 64 + t * 4];
        *(float4*)&X_lds[t >> 4][(t & 15) * 4] = x4;
    }
    __syncthreads();
    const int h = t & 63, grp = t >> 6;     // grp == wave; X row broadcast/wave
    float acc0[4] = {0.f, 0.f, 0.f, 0.f};
    float acc1[4] = {0.f, 0.f, 0.f, 0.f};
#pragma unroll
    for (int f0 = 0; f0 < 64; f0 += 4) {    // fully unrolled: 32 hoisted loads
        const float4 wa = *(const float4*)&Wg[h * 64 + f0];
        const float4 wb = *(const float4*)&Wg[(64 + h) * 64 + f0];
#pragma unroll
        for (int r = 0; r < 4; ++r) {
            const float4 x4 = *(const float4*)&X_lds[grp * 4 + r][f0];
            acc0[r] += wa.x * x4.x + wa.y * x4.y + wa.z * x4.z + wa.w * x4.w;
            acc1[r] += wb.x * x4.x + wb.y * x4.y + wb.z * x4.z + wb.w * x4.w;
        }
    }
#pragma unroll
    for (int r = 0; r < 4; ++r) {
        Wh_lds[0][grp * 4 + r][h] = acc0[r];
        Wh_lds[1][grp * 4 + r][h] = acc1[r];
    }
    __syncthreads();
    {   // logit-term partials: (k,node) x 8 h-groups
        const int r2 = t & 31, qa = t >> 5;
        const int k = r2 >> 4, nd = r2 & 15;
        float ps = 0.f, pd = 0.f;
#pragma unroll
        for (int i = 0; i < 8; ++i) {
            const int hh = qa * 8 + i;
            const float v = Wh_lds[k][nd][hh];
            ps += v * a_src[k * 64 + hh];
            pd += v * a_dst[k * 64 + hh];
        }
        spart[r2][qa][0] = ps;
        spart[r2][qa][1] = pd;
    }
    // whB B-frag store: element (k,h,q): f=h>>4, n=h&15, qb=q>>5, qg=(q>>3)&3,
    // j=q&7; flat = ((k*4+f)*128+qb)*512 + (qg*16+n)*8 + j. Pack 2 bf16/u32.
    {
        const int qb = n0 >> 5;
        const int qgbase = (n0 & 31) >> 3;
#pragma unroll
        for (int it = 0; it < 4; ++it) {
            const int pid = t + it * 256;           // 0..1023
            const int j2 = pid & 3, qgl = (pid >> 2) & 1;
            const int n = (pid >> 3) & 15, f = (pid >> 7) & 3, k = pid >> 9;
            const int i0 = qgl * 8 + j2 * 2;
            const unsigned lo = bf_rne(Wh_lds[k][i0][f * 16 + n]);
            const unsigned hi = bf_rne(Wh_lds[k][i0 + 1][f * 16 + n]);
            unsigned* dst = (unsigned*)&whB[(((k * 4 + f) * 128 + qb) * 512)
                                            + ((qgbase + qgl) * 16 + n) * 8 + j2 * 2];
            *dst = lo | (hi << 16);
        }
    }
    __syncthreads();
    if (t < 32) {
        const int k = t >> 4, nd = t & 15;
        float s0 = 0.f, s1 = 0.f;
#pragma unroll
        for (int qa = 0; qa < 8; ++qa) {
            s0 += spart[t][qa][0];
            s1 += spart[t][qa][1];
        }
        e1s[k * NN + n0 + nd] = __expf(s0);
        e2s[k * NN + n0 + nd] = __expf(0.2f * s0);
        e1d[k * NN + n0 + nd] = __expf(s1);
        e2d[k * NN + n0 + nd] = __expf(0.2f * s1);
    }
}

__global__ __launch_bounds__(1024) void gat_attn(
    const int* __restrict__ adj,
    const unsigned short* __restrict__ whB,
    const float* __restrict__ e1s, const float* __restrict__ e2s,
    const float* __restrict__ e1d, const float* __restrict__ e2d,
    const unsigned short* __restrict__ Wpk, const unsigned short* __restrict__ fcb,
    const float* __restrict__ biasg, const float* __restrict__ fc_b,
    float* __restrict__ out)
{
    __shared__ float S_all[16][2][16][64];              // 128 KB wave partials
    __shared__ float z_all[16][2][16];                  // 2 KB
    __shared__ unsigned short msk_lds[2][16][66];       // 4.1 KB dbuf mask tile
    // post-combine aliases into dead S_all space:
    unsigned short* h_lds = (unsigned short*)&S_all[0][0][0][0];      // [16][136] bf16
    float* gate_lds = (float*)((char*)&S_all[0][0][0][0] + 4608);     // [3][16][68] f32

    const int tid = threadIdx.x;
    const int wave = tid >> 6, lane = tid & 63;
    const int rloc = lane & 15, qg = lane >> 4;
    const int p0 = blockIdx.x * 16;
    const int p = p0 + rloc;

    // wave w streams adj row p0+w; lane l covers q in [c*1024+16l, +16)
    const i32x4* __restrict__ arow = (const i32x4*)(adj + (long)(p0 + wave) * NN);

    // per-lane row factors
    const float e1p0 = e1d[p], e2p0 = e2d[p];
    const float e1p1 = e1d[NN + p], e2p1 = e2d[NN + p];
    const unsigned short* __restrict__ whB_l = whB + lane * 8;

    f32x4 acc[2][4];
#pragma unroll
    for (int k = 0; k < 2; ++k)
#pragma unroll
        for (int f = 0; f < 4; ++f)
            acc[k][f] = (f32x4){0.f, 0.f, 0.f, 0.f};
    float z0 = 0.f, z1 = 0.f;

    // ---- prologue: stage chunk 0 masks ----
    {
        const i32x4 a0 = arow[lane * 4 + 0];
        const i32x4 a1 = arow[lane * 4 + 1];
        const i32x4 a2 = arow[lane * 4 + 2];
        const i32x4 a3 = arow[lane * 4 + 3];
        msk_lds[0][wave][lane] = (unsigned short)pack16(a0, a1, a2, a3);
    }
    __syncthreads();

#pragma unroll
    for (int c = 0; c < 4; ++c) {
        // issue next chunk's adj loads before compute (hides under MFMA/VALU)
        i32x4 n0v, n1v, n2v, n3v;
        if (c < 3) {
            const int base = (c + 1) * 256 + lane * 4;
            n0v = arow[base + 0];
            n1v = arow[base + 1];
            n2v = arow[base + 2];
            n3v = arow[base + 3];
        }
        // ---- compute chunk c: wave handles q in [c*1024 + wave*64, +64) ----
#pragma unroll
        for (int kk = 0; kk < 2; ++kk) {
            const int q0 = c * 1024 + wave * 64 + kk * 32 + qg * 8;
            const int qb = c * 32 + wave * 2 + kk;
            const unsigned mm = msk_lds[c & 1][rloc][wave * 4 + kk * 2 + (qg >> 1)];
            const unsigned byte8 = (mm >> ((qg & 1) * 8)) & 0xffu;
            // q-side factors (L1/L2-hot broadcast arrays)
            const float4 qa0 = *(const float4*)(e1s + q0);
            const float4 qa1 = *(const float4*)(e1s + q0 + 4);
            const float4 qb0 = *(const float4*)(e2s + q0);
            const float4 qb1 = *(const float4*)(e2s + q0 + 4);
            const float4 qc0 = *(const float4*)(e1s + NN + q0);
            const float4 qc1 = *(const float4*)(e1s + NN + q0 + 4);
            const float4 qd0 = *(const float4*)(e2s + NN + q0);
            const float4 qd1 = *(const float4*)(e2s + NN + q0 + 4);
            const float q1v0[8] = {qa0.x, qa0.y, qa0.z, qa0.w, qa1.x, qa1.y, qa1.z, qa1.w};
            const float q2v0[8] = {qb0.x, qb0.y, qb0.z, qb0.w, qb1.x, qb1.y, qb1.z, qb1.w};
            const float q1v1[8] = {qc0.x, qc0.y, qc0.z, qc0.w, qc1.x, qc1.y, qc1.z, qc1.w};
            const float q2v1[8] = {qd0.x, qd0.y, qd0.z, qd0.w, qd1.x, qd1.y, qd1.z, qd1.w};
            float w0a[8], w1a[8];
#pragma unroll
            for (int j = 0; j < 8; ++j) {
                const bool on = (byte8 & (1u << j)) != 0u;
                // w = exp(lrelu(sd+ss)) ; pp=exp(sd+ss) ; pp>1 <=> sd+ss>0
                const float pp0 = e1p0 * q1v0[j];
                float w0 = pp0 > 1.f ? pp0 : e2p0 * q2v0[j];
                w0 = on ? w0 : 0.f;
                z0 += w0;
                w0a[j] = w0;
                const float pp1 = e1p1 * q1v1[j];
                float w1 = pp1 > 1.f ? pp1 : e2p1 * q2v1[j];
                w1 = on ? w1 : 0.f;
                z1 += w1;
                w1a[j] = w1;
            }
            union { bf16x8 v; unsigned w[4]; } fa0, fa1;
#pragma unroll
            for (int i = 0; i < 4; ++i) {
                fa0.w[i] = cvt_pk_bf16(w0a[2 * i], w0a[2 * i + 1]);
                fa1.w[i] = cvt_pk_bf16(w1a[2 * i], w1a[2 * i + 1]);
            }
#pragma unroll
            for (int f = 0; f < 4; ++f) {
                const bf16x8 b0 = *(const bf16x8*)(whB_l + ((f * 128 + qb) << 9));
                acc[0][f] = __builtin_amdgcn_mfma_f32_16x16x32_bf16(fa0.v, b0, acc[0][f], 0, 0, 0);
                const bf16x8 b1 = *(const bf16x8*)(whB_l + (((4 + f) * 128 + qb) << 9));
                acc[1][f] = __builtin_amdgcn_mfma_f32_16x16x32_bf16(fa1.v, b1, acc[1][f], 0, 0, 0);
            }
        }
        if (c < 3) {
            // buffer (c+1)&1 last read in chunk c-1, fenced by that barrier
            msk_lds[(c + 1) & 1][wave][lane] =
                (unsigned short)pack16(n0v, n1v, n2v, n3v);
            __syncthreads();
        }
    }
    // z: sum the 4 q-groups (lanes l, l^16, l^32, l^48 share a row)
    z0 += __shfl_xor(z0, 16); z0 += __shfl_xor(z0, 32);
    z1 += __shfl_xor(z1, 16); z1 += __shfl_xor(z1, 32);
    if (lane < 16) { z_all[wave][0][lane] = z0; z_all[wave][1][lane] = z1; }
    // D-frag layout: row=(l>>4)*4+j, col=l&15
#pragma unroll
    for (int k = 0; k < 2; ++k)
#pragma unroll
        for (int f = 0; f < 4; ++f)
#pragma unroll
            for (int j = 0; j < 4; ++j)
                S_all[wave][k][qg * 4 + j][f * 16 + rloc] = acc[k][f][j];
    __syncthreads();
    // combine 16 wave-partials, normalize, elu -> registers
    float vreg[2]; int vk[2], vr[2], vh[2];
#pragma unroll
    for (int i = 0; i < 2; ++i) {
        const int idx = tid + i * 1024;
        const int k = idx >> 10, rr = (idx >> 6) & 15, hh = idx & 63;
        float s = 0.f, z = 0.f;
#pragma unroll
        for (int w = 0; w < 16; ++w) {
            s += S_all[w][k][rr][hh];
            z += z_all[w][k][rr];
        }
        float v = s / z;
        vreg[i] = v > 0.f ? v : expm1f(v);
        vk[i] = k; vr[i] = rr; vh[i] = hh;
    }
    __syncthreads();    // all S_all reads done; safe to reuse as h_lds/gate_lds
    // h tile bf16 [node][k*64+h], padded row 136 (272B, 16B-aligned rows)
#pragma unroll
    for (int i = 0; i < 2; ++i)
        h_lds[vr[i] * 136 + vk[i] * 64 + vh[i]] = bf_rne(vreg[i]);
    __syncthreads();

    // ---- fused LSTM gates GEMM: 12 waves, one 16-col gate tile each ----
    const int c2 = lane & 15, g4 = lane >> 4;
    if (wave < 12) {
        const int t = wave;
        f32x4 ga = (f32x4){0.f, 0.f, 0.f, 0.f};
#pragma unroll
        for (int k0 = 0; k0 < 4; ++k0) {
            const bf16x8 a = *(const bf16x8*)&h_lds[c2 * 136 + k0 * 32 + g4 * 8];
            const bf16x8 b = *(const bf16x8*)&Wpk[((t * 4 + k0) * 64 + lane) * 8];
            ga = __builtin_amdgcn_mfma_f32_16x16x32_bf16(a, b, ga, 0, 0, 0);
        }
        const float bb = biasg[t * 16 + c2];
#pragma unroll
        for (int j = 0; j < 4; ++j)
            gate_lds[(t >> 2) * 1088 + (g4 * 4 + j) * 68 + (t & 3) * 16 + c2] = ga[j] + bb;
    }
    __syncthreads();
    // ---- LSTM nonlinearity: ht = sig(o)*tanh(sig(i)*tanh(g)) ----
    {
        const int n = tid >> 6, hh = tid & 63;
        const float iv = gate_lds[n * 68 + hh];
        const float gv = gate_lds[1088 + n * 68 + hh];
        const float ov = gate_lds[2176 + n * 68 + hh];
        const float cv = sigf(iv) * tanhf(gv);
        const float htv = sigf(ov) * tanhf(cv);
        __syncthreads();
        h_lds[n * 136 + hh] = bf_rne(htv);   // reuse h_lds (gates consumed h)
    }
    __syncthreads();
    // ---- fc GEMM: waves 0,1 -> out[16 nodes][32] ----
    if (wave < 2) {
        const int t2 = wave;
        f32x4 fa = (f32x4){0.f, 0.f, 0.f, 0.f};
#pragma unroll
        for (int k0 = 0; k0 < 2; ++k0) {
            const bf16x8 a = *(const bf16x8*)&h_lds[c2 * 136 + k0 * 32 + g4 * 8];
            const bf16x8 b = *(const bf16x8*)&fcb[((t2 * 2 + k0) * 64 + lane) * 8];
            fa = __builtin_amdgcn_mfma_f32_16x16x32_bf16(a, b, fa, 0, 0, 0);
        }
        const float fb = fc_b[t2 * 16 + c2];
#pragma unroll
        for (int j = 0; j < 4; ++j)
            out[(p0 + g4 * 4 + j) * 32 + t2 * 16 + c2] = fa[j] + fb;
    }
}

extern "C" void kernel_launch(void* const* d_in, const int* in_sizes, int n_in,
                              void* d_out, int out_size, void* d_ws, size_t ws_size,
                              hipStream_t stream) {
    const float* X     = (const float*)d_in[0];
    const int*   adj   = (const int*)d_in[1];
    // d_in[2] temporal_features: unused by the reference
    const float* Wg    = (const float*)d_in[3];
    const float* a_src = (const float*)d_in[4];
    const float* a_dst = (const float*)d_in[5];
    const float* W_ih  = (const float*)d_in[6];
    // d_in[7] W_hh: unused (h0 == 0)
    const float* b_ih  = (const float*)d_in[8];
    const float* b_hh  = (const float*)d_in[9];
    const float* fc_W  = (const float*)d_in[10];
    const float* fc_b  = (const float*)d_in[11];
    float* out = (float*)d_out;

    char* ws = (char*)d_ws;
    unsigned short* whB = (unsigned short*)ws;                       // 1 MB
    float* e1s = (float*)(ws + (1 << 20));                           // 32 KB
    float* e2s = (float*)(ws + (1 << 20) + (32 << 10));              // 32 KB
    float* e1d = (float*)(ws + (1 << 20) + (64 << 10));              // 32 KB
    float* e2d = (float*)(ws + (1 << 20) + (96 << 10));              // 32 KB
    char* ws2 = ws + (1 << 20) + (128 << 10);
    unsigned short* Wpk = (unsigned short*)ws2;                      // 48 KB
    unsigned short* fcb = (unsigned short*)(ws2 + (48 << 10));       // 4 KB
    float* biasg = (float*)(ws2 + (52 << 10));                       // 768 B

    hipLaunchKernelGGL(prep_parallel, dim3(361), dim3(256), 0, stream,
                       X, Wg, a_src, a_dst, W_ih, b_ih, b_hh, fc_W,
                       whB, e1s, e2s, e1d, e2d, Wpk, fcb, biasg);
    hipLaunchKernelGGL(gat_attn, dim3(256), dim3(1024), 0, stream,
                       adj, whB, e1s, e2s, e1d, e2d, Wpk, fcb, biasg, fc_b, out);
}